// Round 2
// baseline (878.457 us; speedup 1.0000x reference)
//
#include <hip/hip_runtime.h>

// ---------------- CSR construction ----------------

__global__ void k_hist(const int* __restrict__ dst, int* __restrict__ deg, int E) {
  int e = blockIdx.x * 256 + threadIdx.x;
  if (e < E) atomicAdd(&deg[dst[e]], 1);
}

__global__ void k_dinv(const int* __restrict__ deg, float* __restrict__ dinv, int N) {
  int i = blockIdx.x * 256 + threadIdx.x;
  if (i < N) dinv[i] = rsqrtf((float)deg[i] + 1.0f);
}

__global__ void k_scan1(const int* __restrict__ deg, int* __restrict__ rowptr,
                        int* __restrict__ bsum, int N) {
  __shared__ int s[256];
  int t = threadIdx.x;
  int i = blockIdx.x * 256 + t;
  int v = (i < N) ? deg[i] : 0;
  s[t] = v;
  __syncthreads();
  for (int off = 1; off < 256; off <<= 1) {
    int u = (t >= off) ? s[t - off] : 0;
    __syncthreads();
    s[t] += u;
    __syncthreads();
  }
  if (i < N) rowptr[i] = s[t] - v;           // local exclusive scan
  if (t == 255) bsum[blockIdx.x] = s[255];   // block total
}

__global__ void k_scan2(const int* __restrict__ bsum, int* __restrict__ boff, int nb) {
  __shared__ int s[512];
  int t = threadIdx.x;
  int v = (t < nb) ? bsum[t] : 0;
  s[t] = v;
  __syncthreads();
  for (int off = 1; off < 512; off <<= 1) {
    int u = (t >= off) ? s[t - off] : 0;
    __syncthreads();
    s[t] += u;
    __syncthreads();
  }
  boff[t] = s[t] - v;
}

__global__ void k_scan3(int* __restrict__ rowptr, const int* __restrict__ boff,
                        int* __restrict__ cursor, int N, int E) {
  int i = blockIdx.x * 256 + threadIdx.x;
  if (i < N) {
    int r = rowptr[i] + boff[i >> 8];
    rowptr[i] = r;
    cursor[i] = r;
  }
  if (i == 0) rowptr[N] = E;
}

__global__ void k_scatter(const int* __restrict__ src, const int* __restrict__ dst,
                          const float* __restrict__ dinv, int* __restrict__ cursor,
                          int* __restrict__ esrc, float* __restrict__ ew, int E) {
  int e = blockIdx.x * 256 + threadIdx.x;
  if (e >= E) return;
  int s = src[e], d = dst[e];
  float w = dinv[s] * dinv[d];            // enorm
  int pos = atomicAdd(&cursor[d], 1);
  esrc[pos] = s;
  ew[pos] = w;
}

// ---------------- tiny precomputes ----------------

// T[r][c] = embed[r] @ W0  (2 x 128)
__global__ void k_T(const float* __restrict__ embed, const float* __restrict__ W0,
                    float* __restrict__ T) {
  int t = threadIdx.x;
  int r = t >> 7, c = t & 127;
  float acc = 0.f;
  for (int k = 0; k < 128; ++k)
    acc += embed[r * 128 + k] * W0[k * 128 + c];
  T[r * 128 + c] = acc;
}

__global__ void k_initb(int* gstart, int* gend, int G) {
  int g = threadIdx.x;
  if (g < G) { gstart[g] = 0; gend[g] = 0; }
}

__global__ void k_bounds(const int* __restrict__ batch, int* __restrict__ gstart,
                         int* __restrict__ gend, int N) {
  int i = blockIdx.x * 256 + threadIdx.x;
  if (i >= N) return;
  int g = batch[i];
  if (i == 0 || batch[i - 1] != g) gstart[g] = i;
  if (i == N - 1 || batch[i + 1] != g) gend[g] = i + 1;
}

// ---------------- layer 0 (rank-2 shortcut) ----------------
// h1[i] = relu(c0*T0 + c1*T1 + b0), c_k = sum(enorm over in-edges w/ x[src]=k) + snorm*[x[i]==k]
__global__ void k_layer1(const int* __restrict__ x, const int* __restrict__ rowptr,
                         const int* __restrict__ esrc, const float* __restrict__ ew,
                         const float* __restrict__ dinv, const float* __restrict__ T,
                         const float* __restrict__ b0, float* __restrict__ h, int N) {
  int wid = (blockIdx.x * blockDim.x + threadIdx.x) >> 6;
  int lane = threadIdx.x & 63;
  if (wid >= N) return;
  int i = wid;
  int r0 = rowptr[i], r1 = rowptr[i + 1];
  float c0 = 0.f, c1 = 0.f;
  for (int e = r0 + lane; e < r1; e += 64) {
    float w = ew[e];
    int s = esrc[e];
    if (x[s]) c1 += w; else c0 += w;
  }
  for (int m = 32; m >= 1; m >>= 1) {
    c0 += __shfl_xor(c0, m, 64);
    c1 += __shfl_xor(c1, m, 64);
  }
  float di = dinv[i];
  float sn = di * di;
  if (x[i]) c1 += sn; else c0 += sn;
  float* hr = h + (size_t)i * 128;
  for (int j = lane; j < 128; j += 64) {
    float v = c0 * T[j] + c1 * T[128 + j] + b0[j];
    hr[j] = fmaxf(v, 0.f);
  }
}

// ---------------- dense GEMM: t = h @ W (N x 128 x 128) ----------------
__global__ void k_gemm(const float* __restrict__ h, const float* __restrict__ W,
                       float* __restrict__ t, int N) {
  __shared__ float hs[64 * 128];   // 32 KB
  int tid = threadIdx.x;
  int row0 = blockIdx.x * 64;
  for (int idx = tid; idx < 2048; idx += 256) {  // 64 rows * 32 float4
    int row = idx >> 5;
    float4 v = make_float4(0.f, 0.f, 0.f, 0.f);
    if (row0 + row < N)
      v = ((const float4*)(h + (size_t)(row0 + row) * 128))[idx & 31];
    ((float4*)hs)[idx] = v;
  }
  __syncthreads();
  int c = tid & 127;
  int rh = tid >> 7;
  for (int rb = 0; rb < 4; ++rb) {
    int rbase = rh * 32 + rb * 8;
    float acc[8] = {0.f, 0.f, 0.f, 0.f, 0.f, 0.f, 0.f, 0.f};
    for (int k = 0; k < 128; ++k) {
      float wv = W[k * 128 + c];                     // coalesced, L1-resident
      const float* hk = hs + rbase * 128 + k;
      #pragma unroll
      for (int r = 0; r < 8; ++r)
        acc[r] += hk[r * 128] * wv;                  // LDS broadcast
    }
    #pragma unroll
    for (int r = 0; r < 8; ++r) {
      int row = row0 + rbase + r;
      if (row < N) t[(size_t)row * 128 + c] = acc[r];
    }
  }
}

// ---------------- aggregate: h = [relu](A_hat t + b) ----------------
__global__ void k_aggregate(const float* __restrict__ t, const int* __restrict__ rowptr,
                            const int* __restrict__ esrc, const float* __restrict__ ew,
                            const float* __restrict__ dinv, const float* __restrict__ bvec,
                            float* __restrict__ h, int N, int dorelu) {
  int wid = (blockIdx.x * blockDim.x + threadIdx.x) >> 6;
  int lane = threadIdx.x & 63;
  if (wid >= N) return;
  int i = wid;
  int r0 = rowptr[i], r1 = rowptr[i + 1];
  float a0 = 0.f, a1 = 0.f;
  for (int e = r0; e < r1; ++e) {
    int s = esrc[e];
    float w = ew[e];
    const float* tr = t + (size_t)s * 128;
    a0 += w * tr[lane];
    a1 += w * tr[lane + 64];
  }
  float di = dinv[i];
  float sn = di * di;
  const float* ti = t + (size_t)i * 128;
  a0 += sn * ti[lane];
  a1 += sn * ti[lane + 64];
  a0 += bvec[lane];
  a1 += bvec[lane + 64];
  if (dorelu) { a0 = fmaxf(a0, 0.f); a1 = fmaxf(a1, 0.f); }
  float* hr = h + (size_t)i * 128;
  hr[lane] = a0;
  hr[lane + 64] = a1;
}

// ---------------- mean-pool per graph + output head ----------------
__global__ void k_pool_out(const float* __restrict__ h, const int* __restrict__ gstart,
                           const int* __restrict__ gend, const float* __restrict__ W_out,
                           const float* __restrict__ b_out, float* __restrict__ out, int G) {
  __shared__ float sp[128];
  int g = blockIdx.x;
  int j = threadIdx.x;  // 0..127
  int s0 = gstart[g], e1 = gend[g];
  float acc = 0.f;
  for (int i = s0; i < e1; ++i) acc += h[(size_t)i * 128 + j];
  float cnt = (float)(e1 - s0);
  sp[j] = acc / fmaxf(cnt, 1.f);
  __syncthreads();
  if (j < 2) {
    float o = b_out[j];
    for (int k = 0; k < 128; ++k)
      o += sp[k] * W_out[k * 2 + j];
    out[g * 2 + j] = o;
  }
}

extern "C" void kernel_launch(void* const* d_in, const int* in_sizes, int n_in,
                              void* d_out, int out_size, void* d_ws, size_t ws_size,
                              hipStream_t stream) {
  const int*   x     = (const int*)d_in[0];
  const int*   ei    = (const int*)d_in[1];
  const int*   batch = (const int*)d_in[2];
  const float* embed = (const float*)d_in[3];
  const float* Ws    = (const float*)d_in[4];
  const float* bs    = (const float*)d_in[5];
  const float* W_out = (const float*)d_in[6];
  const float* b_out = (const float*)d_in[7];
  float* out = (float*)d_out;

  int N = in_sizes[2];
  int E = in_sizes[1] / 2;
  int G = out_size / 2;

  const int* src = ei;
  const int* dst = ei + E;

  char* w = (char*)d_ws;
  auto alloc = [&](size_t bytes) {
    char* p = w;
    w += (bytes + 255) & ~(size_t)255;
    return p;
  };
  int*   deg    = (int*)  alloc((size_t)N * 4);
  float* dinv   = (float*)alloc((size_t)N * 4);
  int*   rowptr = (int*)  alloc((size_t)(N + 1) * 4);
  int*   cursor = (int*)  alloc((size_t)N * 4);
  int*   bsum   = (int*)  alloc(512 * 4);
  int*   boff   = (int*)  alloc(512 * 4);
  int*   gstart = (int*)  alloc((size_t)G * 4);
  int*   gend   = (int*)  alloc((size_t)G * 4);
  float* T      = (float*)alloc(256 * 4);
  int*   esrc   = (int*)  alloc((size_t)E * 4);
  float* eww    = (float*)alloc((size_t)E * 4);
  float* h      = (float*)alloc((size_t)N * 128 * 4);
  float* t      = (float*)alloc((size_t)N * 128 * 4);

  int nbN = (N + 255) / 256;
  int nbE = (E + 255) / 256;
  int nwb = (N + 3) / 4;   // wave-per-node blocks (4 waves / 256 threads)

  hipMemsetAsync(deg, 0, (size_t)N * 4, stream);
  k_hist<<<nbE, 256, 0, stream>>>(dst, deg, E);
  k_dinv<<<nbN, 256, 0, stream>>>(deg, dinv, N);
  k_scan1<<<nbN, 256, 0, stream>>>(deg, rowptr, bsum, N);
  k_scan2<<<1, 512, 0, stream>>>(bsum, boff, nbN);
  k_scan3<<<nbN, 256, 0, stream>>>(rowptr, boff, cursor, N, E);
  k_scatter<<<nbE, 256, 0, stream>>>(src, dst, dinv, cursor, esrc, eww, E);
  k_T<<<1, 256, 0, stream>>>(embed, Ws, T);
  k_initb<<<1, 256, 0, stream>>>(gstart, gend, G);
  k_bounds<<<nbN, 256, 0, stream>>>(batch, gstart, gend, N);

  k_layer1<<<nwb, 256, 0, stream>>>(x, rowptr, esrc, eww, dinv, T, bs, h, N);

  for (int l = 1; l < 4; ++l) {
    k_gemm<<<(N + 63) / 64, 256, 0, stream>>>(h, Ws + (size_t)l * 128 * 128, t, N);
    k_aggregate<<<nwb, 256, 0, stream>>>(t, rowptr, esrc, eww, dinv, bs + (size_t)l * 128,
                                         h, N, (l < 3) ? 1 : 0);
  }
  k_pool_out<<<G, 128, 0, stream>>>(h, gstart, gend, W_out, b_out, out, G);
}

// Round 3
// 724.744 us; speedup vs baseline: 1.2121x; 1.2121x over previous
//
#include <hip/hip_runtime.h>

// ---------------- CSR construction ----------------

__global__ void k_hist(const int* __restrict__ dst, int* __restrict__ deg, int E) {
  int e = blockIdx.x * 256 + threadIdx.x;
  if (e < E) atomicAdd(&deg[dst[e]], 1);
}

__global__ void k_dinv(const int* __restrict__ deg, float* __restrict__ dinv, int N) {
  int i = blockIdx.x * 256 + threadIdx.x;
  if (i < N) dinv[i] = rsqrtf((float)deg[i] + 1.0f);
}

__global__ void k_scan1(const int* __restrict__ deg, int* __restrict__ rowptr,
                        int* __restrict__ bsum, int N) {
  __shared__ int s[256];
  int t = threadIdx.x;
  int i = blockIdx.x * 256 + t;
  int v = (i < N) ? deg[i] : 0;
  s[t] = v;
  __syncthreads();
  for (int off = 1; off < 256; off <<= 1) {
    int u = (t >= off) ? s[t - off] : 0;
    __syncthreads();
    s[t] += u;
    __syncthreads();
  }
  if (i < N) rowptr[i] = s[t] - v;           // local exclusive scan
  if (t == 255) bsum[blockIdx.x] = s[255];   // block total
}

__global__ void k_scan2(const int* __restrict__ bsum, int* __restrict__ boff, int nb) {
  __shared__ int s[512];
  int t = threadIdx.x;
  int v = (t < nb) ? bsum[t] : 0;
  s[t] = v;
  __syncthreads();
  for (int off = 1; off < 512; off <<= 1) {
    int u = (t >= off) ? s[t - off] : 0;
    __syncthreads();
    s[t] += u;
    __syncthreads();
  }
  boff[t] = s[t] - v;
}

__global__ void k_scan3(int* __restrict__ rowptr, const int* __restrict__ boff,
                        int* __restrict__ cursor, int N, int E) {
  int i = blockIdx.x * 256 + threadIdx.x;
  if (i < N) {
    int r = rowptr[i] + boff[i >> 8];
    rowptr[i] = r;
    cursor[i] = r;
  }
  if (i == 0) rowptr[N] = E;
}

__global__ void k_scatter(const int* __restrict__ src, const int* __restrict__ dst,
                          const float* __restrict__ dinv, int* __restrict__ cursor,
                          int* __restrict__ esrc, float* __restrict__ ew, int E) {
  int e = blockIdx.x * 256 + threadIdx.x;
  if (e >= E) return;
  int s = src[e], d = dst[e];
  float w = dinv[s] * dinv[d];            // enorm
  int pos = atomicAdd(&cursor[d], 1);
  esrc[pos] = s;
  ew[pos] = w;
}

// ---------------- tiny precomputes ----------------

// T[r][c] = embed[r] @ W0  (2 x 128)
__global__ void k_T(const float* __restrict__ embed, const float* __restrict__ W0,
                    float* __restrict__ T) {
  int t = threadIdx.x;
  int r = t >> 7, c = t & 127;
  float acc = 0.f;
  for (int k = 0; k < 128; ++k)
    acc += embed[r * 128 + k] * W0[k * 128 + c];
  T[r * 128 + c] = acc;
}

__global__ void k_initb(int* gstart, int* gend, float* pooled, int G) {
  int g = blockIdx.x * 256 + threadIdx.x;
  if (g < G) { gstart[g] = 0; gend[g] = 0; }
  if (g < G * 128) pooled[g] = 0.f;
}

__global__ void k_bounds(const int* __restrict__ batch, int* __restrict__ gstart,
                         int* __restrict__ gend, int N) {
  int i = blockIdx.x * 256 + threadIdx.x;
  if (i >= N) return;
  int g = batch[i];
  if (i == 0 || batch[i - 1] != g) gstart[g] = i;
  if (i == N - 1 || batch[i + 1] != g) gend[g] = i + 1;
}

// ---------------- layer 0 (rank-2 shortcut) ----------------
__global__ void k_layer1(const int* __restrict__ x, const int* __restrict__ rowptr,
                         const int* __restrict__ esrc, const float* __restrict__ ew,
                         const float* __restrict__ dinv, const float* __restrict__ T,
                         const float* __restrict__ b0, float* __restrict__ h, int N) {
  int wid = (blockIdx.x * blockDim.x + threadIdx.x) >> 6;
  int lane = threadIdx.x & 63;
  if (wid >= N) return;
  int i = wid;
  int r0 = rowptr[i], r1 = rowptr[i + 1];
  float c0 = 0.f, c1 = 0.f;
  for (int e = r0 + lane; e < r1; e += 64) {
    float w = ew[e];
    int s = esrc[e];
    if (x[s]) c1 += w; else c0 += w;
  }
  for (int m = 32; m >= 1; m >>= 1) {
    c0 += __shfl_xor(c0, m, 64);
    c1 += __shfl_xor(c1, m, 64);
  }
  float di = dinv[i];
  float sn = di * di;
  if (x[i]) c1 += sn; else c0 += sn;
  float* hr = h + (size_t)i * 128;
  for (int j = lane; j < 128; j += 64) {
    float v = c0 * T[j] + c1 * T[128 + j] + b0[j];
    hr[j] = fmaxf(v, 0.f);
  }
}

// ---------------- dense GEMM: t = h @ W (N x 128 x 128) ----------------
__global__ void k_gemm(const float* __restrict__ h, const float* __restrict__ W,
                       float* __restrict__ t, int N) {
  __shared__ float hs[64 * 128];   // 32 KB
  int tid = threadIdx.x;
  int row0 = blockIdx.x * 64;
  for (int idx = tid; idx < 2048; idx += 256) {  // 64 rows * 32 float4
    int row = idx >> 5;
    float4 v = make_float4(0.f, 0.f, 0.f, 0.f);
    if (row0 + row < N)
      v = ((const float4*)(h + (size_t)(row0 + row) * 128))[idx & 31];
    ((float4*)hs)[idx] = v;
  }
  __syncthreads();
  int c = tid & 127;
  int rh = tid >> 7;
  for (int rb = 0; rb < 4; ++rb) {
    int rbase = rh * 32 + rb * 8;
    float acc[8] = {0.f, 0.f, 0.f, 0.f, 0.f, 0.f, 0.f, 0.f};
    for (int k = 0; k < 128; k += 4) {
      float w0 = W[(k + 0) * 128 + c];   // coalesced, L1-resident
      float w1 = W[(k + 1) * 128 + c];
      float w2 = W[(k + 2) * 128 + c];
      float w3 = W[(k + 3) * 128 + c];
      #pragma unroll
      for (int r = 0; r < 8; ++r) {
        float4 hv = *(const float4*)(hs + (rbase + r) * 128 + k);  // ds_read_b128 broadcast
        acc[r] += hv.x * w0 + hv.y * w1 + hv.z * w2 + hv.w * w3;
      }
    }
    #pragma unroll
    for (int r = 0; r < 8; ++r) {
      int row = row0 + rbase + r;
      if (row < N) t[(size_t)row * 128 + c] = acc[r];
    }
  }
}

// ---------------- aggregate: h = [relu](A_hat t + b) ----------------
__global__ void k_aggregate(const float* __restrict__ t, const int* __restrict__ rowptr,
                            const int* __restrict__ esrc, const float* __restrict__ ew,
                            const float* __restrict__ dinv, const float* __restrict__ bvec,
                            float* __restrict__ h, int N, int dorelu) {
  int wid = (blockIdx.x * blockDim.x + threadIdx.x) >> 6;
  int lane = threadIdx.x & 63;
  if (wid >= N) return;
  int i = wid;
  int r0 = rowptr[i], r1 = rowptr[i + 1];
  float a0 = 0.f, a1 = 0.f;
  for (int e = r0; e < r1; ++e) {
    int s = esrc[e];
    float w = ew[e];
    const float* tr = t + (size_t)s * 128;
    a0 += w * tr[lane];
    a1 += w * tr[lane + 64];
  }
  float di = dinv[i];
  float sn = di * di;
  const float* ti = t + (size_t)i * 128;
  a0 += sn * ti[lane];
  a1 += sn * ti[lane + 64];
  a0 += bvec[lane];
  a1 += bvec[lane + 64];
  if (dorelu) { a0 = fmaxf(a0, 0.f); a1 = fmaxf(a1, 0.f); }
  float* hr = h + (size_t)i * 128;
  hr[lane] = a0;
  hr[lane + 64] = a1;
}

// ---------------- mean-pool: parallel partial sums ----------------
// Each block covers 64 rows; 256 threads = 2 row-groups x 128 columns.
// batch is sorted, so within a chunk we run-length accumulate and flush
// one atomicAdd per (segment boundary, column).
__global__ void k_pool_partial(const float* __restrict__ h, const int* __restrict__ batch,
                               float* __restrict__ pooled, int N) {
  int c = threadIdx.x & 127;
  int half = threadIdx.x >> 7;               // 0 or 1
  int rbeg = blockIdx.x * 64 + half * 32;
  int rend = rbeg + 32;
  if (rend > N) rend = N;
  if (rbeg >= N) return;
  float acc = 0.f;
  int curg = batch[rbeg];
  for (int i = rbeg; i < rend; ++i) {
    int g = batch[i];
    if (g != curg) {
      atomicAdd(&pooled[curg * 128 + c], acc);
      acc = 0.f;
      curg = g;
    }
    acc += h[(size_t)i * 128 + c];
  }
  atomicAdd(&pooled[curg * 128 + c], acc);
}

// ---------------- output head ----------------
__global__ void k_out(const float* __restrict__ pooled, const int* __restrict__ gstart,
                      const int* __restrict__ gend, const float* __restrict__ W_out,
                      const float* __restrict__ b_out, float* __restrict__ out, int G) {
  __shared__ float sp[128];
  int g = blockIdx.x;
  int j = threadIdx.x;  // 0..127
  float cnt = (float)(gend[g] - gstart[g]);
  sp[j] = pooled[g * 128 + j] / fmaxf(cnt, 1.f);
  __syncthreads();
  if (j < 2) {
    float o = b_out[j];
    for (int k = 0; k < 128; ++k)
      o += sp[k] * W_out[k * 2 + j];
    out[g * 2 + j] = o;
  }
}

extern "C" void kernel_launch(void* const* d_in, const int* in_sizes, int n_in,
                              void* d_out, int out_size, void* d_ws, size_t ws_size,
                              hipStream_t stream) {
  const int*   x     = (const int*)d_in[0];
  const int*   ei    = (const int*)d_in[1];
  const int*   batch = (const int*)d_in[2];
  const float* embed = (const float*)d_in[3];
  const float* Ws    = (const float*)d_in[4];
  const float* bs    = (const float*)d_in[5];
  const float* W_out = (const float*)d_in[6];
  const float* b_out = (const float*)d_in[7];
  float* out = (float*)d_out;

  int N = in_sizes[2];
  int E = in_sizes[1] / 2;
  int G = out_size / 2;

  const int* src = ei;
  const int* dst = ei + E;

  char* w = (char*)d_ws;
  auto alloc = [&](size_t bytes) {
    char* p = w;
    w += (bytes + 255) & ~(size_t)255;
    return p;
  };
  int*   deg    = (int*)  alloc((size_t)N * 4);
  float* dinv   = (float*)alloc((size_t)N * 4);
  int*   rowptr = (int*)  alloc((size_t)(N + 1) * 4);
  int*   cursor = (int*)  alloc((size_t)N * 4);
  int*   bsum   = (int*)  alloc(512 * 4);
  int*   boff   = (int*)  alloc(512 * 4);
  int*   gstart = (int*)  alloc((size_t)G * 4);
  int*   gend   = (int*)  alloc((size_t)G * 4);
  float* T      = (float*)alloc(256 * 4);
  float* pooled = (float*)alloc((size_t)G * 128 * 4);
  int*   esrc   = (int*)  alloc((size_t)E * 4);
  float* eww    = (float*)alloc((size_t)E * 4);
  float* h      = (float*)alloc((size_t)N * 128 * 4);
  float* t      = (float*)alloc((size_t)N * 128 * 4);

  int nbN = (N + 255) / 256;
  int nbE = (E + 255) / 256;
  int nwb = (N + 3) / 4;   // wave-per-node blocks (4 waves / 256 threads)

  hipMemsetAsync(deg, 0, (size_t)N * 4, stream);
  k_hist<<<nbE, 256, 0, stream>>>(dst, deg, E);
  k_dinv<<<nbN, 256, 0, stream>>>(deg, dinv, N);
  k_scan1<<<nbN, 256, 0, stream>>>(deg, rowptr, bsum, N);
  k_scan2<<<1, 512, 0, stream>>>(bsum, boff, nbN);
  k_scan3<<<nbN, 256, 0, stream>>>(rowptr, boff, cursor, N, E);
  k_scatter<<<nbE, 256, 0, stream>>>(src, dst, dinv, cursor, esrc, eww, E);
  k_T<<<1, 256, 0, stream>>>(embed, Ws, T);
  k_initb<<<(G * 128 + 255) / 256, 256, 0, stream>>>(gstart, gend, pooled, G);
  k_bounds<<<nbN, 256, 0, stream>>>(batch, gstart, gend, N);

  k_layer1<<<nwb, 256, 0, stream>>>(x, rowptr, esrc, eww, dinv, T, bs, h, N);

  for (int l = 1; l < 4; ++l) {
    k_gemm<<<(N + 63) / 64, 256, 0, stream>>>(h, Ws + (size_t)l * 128 * 128, t, N);
    k_aggregate<<<nwb, 256, 0, stream>>>(t, rowptr, esrc, eww, dinv, bs + (size_t)l * 128,
                                         h, N, (l < 3) ? 1 : 0);
  }
  k_pool_partial<<<(N + 63) / 64, 256, 0, stream>>>(h, batch, pooled, N);
  k_out<<<G, 128, 0, stream>>>(pooled, gstart, gend, W_out, b_out, out, G);
}

// Round 4
// 544.866 us; speedup vs baseline: 1.6122x; 1.3301x over previous
//
#include <hip/hip_runtime.h>

typedef __attribute__((ext_vector_type(8))) short bf16x8;
typedef __attribute__((ext_vector_type(4))) float f32x4;

// split fp32 into hi/lo bf16 (truncation split; hi+lo ≈ f to ~2^-16 rel)
__device__ inline void split_bf16(float f, unsigned short& hi, unsigned short& lo) {
  unsigned u = __float_as_uint(f);
  hi = (unsigned short)(u >> 16);
  float fh = __uint_as_float(u & 0xffff0000u);
  lo = (unsigned short)(__float_as_uint(f - fh) >> 16);
}

__device__ inline float recon_bf16(unsigned short hi, unsigned short lo) {
  return __uint_as_float((unsigned)hi << 16) + __uint_as_float((unsigned)lo << 16);
}

// ---------------- CSR construction ----------------

__global__ void k_hist(const int* __restrict__ dst, int* __restrict__ deg, int E) {
  int e = blockIdx.x * 256 + threadIdx.x;
  if (e < E) atomicAdd(&deg[dst[e]], 1);
}

__global__ void k_dinv(const int* __restrict__ deg, float* __restrict__ dinv, int N) {
  int i = blockIdx.x * 256 + threadIdx.x;
  if (i < N) dinv[i] = rsqrtf((float)deg[i] + 1.0f);
}

__global__ void k_scan1(const int* __restrict__ deg, int* __restrict__ rowptr,
                        int* __restrict__ bsum, int N) {
  __shared__ int s[256];
  int t = threadIdx.x;
  int i = blockIdx.x * 256 + t;
  int v = (i < N) ? deg[i] : 0;
  s[t] = v;
  __syncthreads();
  for (int off = 1; off < 256; off <<= 1) {
    int u = (t >= off) ? s[t - off] : 0;
    __syncthreads();
    s[t] += u;
    __syncthreads();
  }
  if (i < N) rowptr[i] = s[t] - v;
  if (t == 255) bsum[blockIdx.x] = s[255];
}

__global__ void k_scan2(const int* __restrict__ bsum, int* __restrict__ boff, int nb) {
  __shared__ int s[512];
  int t = threadIdx.x;
  int v = (t < nb) ? bsum[t] : 0;
  s[t] = v;
  __syncthreads();
  for (int off = 1; off < 512; off <<= 1) {
    int u = (t >= off) ? s[t - off] : 0;
    __syncthreads();
    s[t] += u;
    __syncthreads();
  }
  boff[t] = s[t] - v;
}

__global__ void k_scan3(int* __restrict__ rowptr, const int* __restrict__ boff,
                        int* __restrict__ cursor, int N, int E) {
  int i = blockIdx.x * 256 + threadIdx.x;
  if (i < N) {
    int r = rowptr[i] + boff[i >> 8];
    rowptr[i] = r;
    cursor[i] = r;
  }
  if (i == 0) rowptr[N] = E;
}

__global__ void k_scatter(const int* __restrict__ src, const int* __restrict__ dst,
                          const float* __restrict__ dinv, int* __restrict__ cursor,
                          int* __restrict__ esrc, float* __restrict__ ew, int E) {
  int e = blockIdx.x * 256 + threadIdx.x;
  if (e >= E) return;
  int s = src[e], d = dst[e];
  float w = dinv[s] * dinv[d];
  int pos = atomicAdd(&cursor[d], 1);
  esrc[pos] = s;
  ew[pos] = w;
}

// ---------------- tiny precomputes ----------------

// T[r][c] = embed[r] @ W0  (2 x 128)
__global__ void k_T(const float* __restrict__ embed, const float* __restrict__ W0,
                    float* __restrict__ T) {
  int t = threadIdx.x;
  int r = t >> 7, c = t & 127;
  float acc = 0.f;
  for (int k = 0; k < 128; ++k)
    acc += embed[r * 128 + k] * W0[k * 128 + c];
  T[r * 128 + c] = acc;
}

// Pre-swizzle W (layers 1..3) into MFMA B-fragment order, split hi/lo.
// dest idx layout: ((ct*4 + c)*64 + lane)*8 + j  maps to  W[k][n],
// k = c*32 + (lane>>4)*8 + j, n = ct*16 + (lane&15).
__global__ void k_prepW(const float* __restrict__ Ws,
                        unsigned short* __restrict__ wphi,
                        unsigned short* __restrict__ wplo) {
  int l = blockIdx.x;              // 0..2 -> layers 1..3
  const float* W = Ws + (size_t)(l + 1) * 128 * 128;
  unsigned short* dh = wphi + (size_t)l * 16384;
  unsigned short* dl = wplo + (size_t)l * 16384;
  for (int idx = threadIdx.x; idx < 16384; idx += 256) {
    int j = idx & 7;
    int lane = (idx >> 3) & 63;
    int c = (idx >> 9) & 3;
    int ct = idx >> 11;
    int k = c * 32 + ((lane >> 4) * 8) + j;
    int n = ct * 16 + (lane & 15);
    unsigned short hi, lo;
    split_bf16(W[k * 128 + n], hi, lo);
    dh[idx] = hi;
    dl[idx] = lo;
  }
}

__global__ void k_initb(int* gstart, int* gend, float* pooled, int G) {
  int g = blockIdx.x * 256 + threadIdx.x;
  if (g < G) { gstart[g] = 0; gend[g] = 0; }
  if (g < G * 128) pooled[g] = 0.f;
}

__global__ void k_bounds(const int* __restrict__ batch, int* __restrict__ gstart,
                         int* __restrict__ gend, int N) {
  int i = blockIdx.x * 256 + threadIdx.x;
  if (i >= N) return;
  int g = batch[i];
  if (i == 0 || batch[i - 1] != g) gstart[g] = i;
  if (i == N - 1 || batch[i + 1] != g) gend[g] = i + 1;
}

// ---------------- layer 0 (rank-2 shortcut) ----------------
__global__ void k_layer1(const int* __restrict__ x, const int* __restrict__ rowptr,
                         const int* __restrict__ esrc, const float* __restrict__ ew,
                         const float* __restrict__ dinv, const float* __restrict__ T,
                         const float* __restrict__ b0,
                         unsigned short* __restrict__ hhi,
                         unsigned short* __restrict__ hlo, int N) {
  int wid = (blockIdx.x * blockDim.x + threadIdx.x) >> 6;
  int lane = threadIdx.x & 63;
  if (wid >= N) return;
  int i = wid;
  int r0 = rowptr[i], r1 = rowptr[i + 1];
  float c0 = 0.f, c1 = 0.f;
  for (int e = r0 + lane; e < r1; e += 64) {
    float w = ew[e];
    int s = esrc[e];
    if (x[s]) c1 += w; else c0 += w;
  }
  for (int m = 32; m >= 1; m >>= 1) {
    c0 += __shfl_xor(c0, m, 64);
    c1 += __shfl_xor(c1, m, 64);
  }
  float di = dinv[i];
  float sn = di * di;
  if (x[i]) c1 += sn; else c0 += sn;
  for (int j = lane; j < 128; j += 64) {
    float v = c0 * T[j] + c1 * T[128 + j] + b0[j];
    v = fmaxf(v, 0.f);
    unsigned short hi, lo;
    split_bf16(v, hi, lo);
    hhi[(size_t)i * 128 + j] = hi;
    hlo[(size_t)i * 128 + j] = lo;
  }
}

// ---------------- MFMA split-bf16 GEMM: t = (hhi+hlo) @ W (N x 128 x 128) ----------------
// One wave = 2 row-tiles of 16 rows; no LDS. A-frags direct from global
// (16x64B segments, L1-cached); B-frags from pre-swizzled W' (1KB/instr coalesced).
__global__ void k_gemm_mfma(const unsigned short* __restrict__ hhi,
                            const unsigned short* __restrict__ hlo,
                            const unsigned short* __restrict__ wphi,
                            const unsigned short* __restrict__ wplo,
                            float* __restrict__ t, int N) {
  int wave = threadIdx.x >> 6;
  int lane = threadIdx.x & 63;
  int job = blockIdx.x * 4 + wave;
  int r0 = job * 32;
  if (r0 >= N) return;
  int q = lane >> 4;
  int m = lane & 15;

  f32x4 acc[2][8];
  #pragma unroll
  for (int tt = 0; tt < 2; ++tt)
    #pragma unroll
    for (int ct = 0; ct < 8; ++ct)
      acc[tt][ct] = (f32x4){0.f, 0.f, 0.f, 0.f};

  const bf16x8* bh_base = (const bf16x8*)wphi;
  const bf16x8* bl_base = (const bf16x8*)wplo;

  for (int c = 0; c < 4; ++c) {
    size_t ka = (size_t)(r0 + m) * 128 + c * 32 + q * 8;
    size_t kb = (size_t)(r0 + 16 + m) * 128 + c * 32 + q * 8;
    bf16x8 ah0 = *(const bf16x8*)(hhi + ka);
    bf16x8 al0 = *(const bf16x8*)(hlo + ka);
    bf16x8 ah1 = *(const bf16x8*)(hhi + kb);
    bf16x8 al1 = *(const bf16x8*)(hlo + kb);
    #pragma unroll
    for (int ct = 0; ct < 8; ++ct) {
      bf16x8 bh = bh_base[(ct * 4 + c) * 64 + lane];
      bf16x8 bl = bl_base[(ct * 4 + c) * 64 + lane];
      acc[0][ct] = __builtin_amdgcn_mfma_f32_16x16x32_bf16(ah0, bh, acc[0][ct], 0, 0, 0);
      acc[0][ct] = __builtin_amdgcn_mfma_f32_16x16x32_bf16(al0, bh, acc[0][ct], 0, 0, 0);
      acc[0][ct] = __builtin_amdgcn_mfma_f32_16x16x32_bf16(ah0, bl, acc[0][ct], 0, 0, 0);
      acc[1][ct] = __builtin_amdgcn_mfma_f32_16x16x32_bf16(ah1, bh, acc[1][ct], 0, 0, 0);
      acc[1][ct] = __builtin_amdgcn_mfma_f32_16x16x32_bf16(al1, bh, acc[1][ct], 0, 0, 0);
      acc[1][ct] = __builtin_amdgcn_mfma_f32_16x16x32_bf16(ah1, bl, acc[1][ct], 0, 0, 0);
    }
  }

  #pragma unroll
  for (int tt = 0; tt < 2; ++tt)
    #pragma unroll
    for (int ct = 0; ct < 8; ++ct)
      #pragma unroll
      for (int r = 0; r < 4; ++r) {
        int row = r0 + tt * 16 + q * 4 + r;
        t[(size_t)row * 128 + ct * 16 + m] = acc[tt][ct][r];
      }
}

// ---------------- aggregate: h = [relu](A_hat t + b), write hi/lo ----------------
__global__ void k_aggregate(const float* __restrict__ t, const int* __restrict__ rowptr,
                            const int* __restrict__ esrc, const float* __restrict__ ew,
                            const float* __restrict__ dinv, const float* __restrict__ bvec,
                            unsigned short* __restrict__ hhi,
                            unsigned short* __restrict__ hlo, int N, int dorelu) {
  int wid = (blockIdx.x * blockDim.x + threadIdx.x) >> 6;
  int lane = threadIdx.x & 63;
  if (wid >= N) return;
  int i = wid;
  int r0 = rowptr[i], r1 = rowptr[i + 1];
  float a0 = 0.f, a1 = 0.f;
  for (int e = r0; e < r1; ++e) {
    int s = esrc[e];
    float w = ew[e];
    const float* tr = t + (size_t)s * 128;
    a0 += w * tr[lane];
    a1 += w * tr[lane + 64];
  }
  float di = dinv[i];
  float sn = di * di;
  const float* ti = t + (size_t)i * 128;
  a0 += sn * ti[lane];
  a1 += sn * ti[lane + 64];
  a0 += bvec[lane];
  a1 += bvec[lane + 64];
  if (dorelu) { a0 = fmaxf(a0, 0.f); a1 = fmaxf(a1, 0.f); }
  unsigned short hi, lo;
  split_bf16(a0, hi, lo);
  hhi[(size_t)i * 128 + lane] = hi;
  hlo[(size_t)i * 128 + lane] = lo;
  split_bf16(a1, hi, lo);
  hhi[(size_t)i * 128 + lane + 64] = hi;
  hlo[(size_t)i * 128 + lane + 64] = lo;
}

// ---------------- mean-pool: parallel partial sums ----------------
__global__ void k_pool_partial(const unsigned short* __restrict__ hhi,
                               const unsigned short* __restrict__ hlo,
                               const int* __restrict__ batch,
                               float* __restrict__ pooled, int N) {
  int c = threadIdx.x & 127;
  int half = threadIdx.x >> 7;
  int rbeg = blockIdx.x * 64 + half * 32;
  int rend = rbeg + 32;
  if (rend > N) rend = N;
  if (rbeg >= N) return;
  float acc = 0.f;
  int curg = batch[rbeg];
  for (int i = rbeg; i < rend; ++i) {
    int g = batch[i];
    if (g != curg) {
      atomicAdd(&pooled[curg * 128 + c], acc);
      acc = 0.f;
      curg = g;
    }
    acc += recon_bf16(hhi[(size_t)i * 128 + c], hlo[(size_t)i * 128 + c]);
  }
  atomicAdd(&pooled[curg * 128 + c], acc);
}

// ---------------- output head ----------------
__global__ void k_out(const float* __restrict__ pooled, const int* __restrict__ gstart,
                      const int* __restrict__ gend, const float* __restrict__ W_out,
                      const float* __restrict__ b_out, float* __restrict__ out, int G) {
  __shared__ float sp[128];
  int g = blockIdx.x;
  int j = threadIdx.x;
  float cnt = (float)(gend[g] - gstart[g]);
  sp[j] = pooled[g * 128 + j] / fmaxf(cnt, 1.f);
  __syncthreads();
  if (j < 2) {
    float o = b_out[j];
    for (int k = 0; k < 128; ++k)
      o += sp[k] * W_out[k * 2 + j];
    out[g * 2 + j] = o;
  }
}

extern "C" void kernel_launch(void* const* d_in, const int* in_sizes, int n_in,
                              void* d_out, int out_size, void* d_ws, size_t ws_size,
                              hipStream_t stream) {
  const int*   x     = (const int*)d_in[0];
  const int*   ei    = (const int*)d_in[1];
  const int*   batch = (const int*)d_in[2];
  const float* embed = (const float*)d_in[3];
  const float* Ws    = (const float*)d_in[4];
  const float* bs    = (const float*)d_in[5];
  const float* W_out = (const float*)d_in[6];
  const float* b_out = (const float*)d_in[7];
  float* out = (float*)d_out;

  int N = in_sizes[2];
  int E = in_sizes[1] / 2;
  int G = out_size / 2;

  const int* src = ei;
  const int* dst = ei + E;

  char* w = (char*)d_ws;
  auto alloc = [&](size_t bytes) {
    char* p = w;
    w += (bytes + 255) & ~(size_t)255;
    return p;
  };
  int*   deg    = (int*)  alloc((size_t)N * 4);
  float* dinv   = (float*)alloc((size_t)N * 4);
  int*   rowptr = (int*)  alloc((size_t)(N + 1) * 4);
  int*   cursor = (int*)  alloc((size_t)N * 4);
  int*   bsum   = (int*)  alloc(512 * 4);
  int*   boff   = (int*)  alloc(512 * 4);
  int*   gstart = (int*)  alloc((size_t)G * 4);
  int*   gend   = (int*)  alloc((size_t)G * 4);
  float* T      = (float*)alloc(256 * 4);
  float* pooled = (float*)alloc((size_t)G * 128 * 4);
  unsigned short* wphi = (unsigned short*)alloc((size_t)3 * 16384 * 2);
  unsigned short* wplo = (unsigned short*)alloc((size_t)3 * 16384 * 2);
  int*   esrc   = (int*)  alloc((size_t)E * 4);
  float* eww    = (float*)alloc((size_t)E * 4);
  unsigned short* hhi = (unsigned short*)alloc((size_t)N * 128 * 2);
  unsigned short* hlo = (unsigned short*)alloc((size_t)N * 128 * 2);
  float* t      = (float*)alloc((size_t)N * 128 * 4);

  int nbN = (N + 255) / 256;
  int nbE = (E + 255) / 256;
  int nwb = (N + 3) / 4;

  hipMemsetAsync(deg, 0, (size_t)N * 4, stream);
  k_hist<<<nbE, 256, 0, stream>>>(dst, deg, E);
  k_dinv<<<nbN, 256, 0, stream>>>(deg, dinv, N);
  k_scan1<<<nbN, 256, 0, stream>>>(deg, rowptr, bsum, N);
  k_scan2<<<1, 512, 0, stream>>>(bsum, boff, nbN);
  k_scan3<<<nbN, 256, 0, stream>>>(rowptr, boff, cursor, N, E);
  k_scatter<<<nbE, 256, 0, stream>>>(src, dst, dinv, cursor, esrc, eww, E);
  k_T<<<1, 256, 0, stream>>>(embed, Ws, T);
  k_prepW<<<3, 256, 0, stream>>>(Ws, wphi, wplo);
  k_initb<<<(G * 128 + 255) / 256, 256, 0, stream>>>(gstart, gend, pooled, G);
  k_bounds<<<nbN, 256, 0, stream>>>(batch, gstart, gend, N);

  k_layer1<<<nwb, 256, 0, stream>>>(x, rowptr, esrc, eww, dinv, T, bs, hhi, hlo, N);

  int gemm_blocks = (N / 32 + 3) / 4 + 1;
  for (int l = 1; l < 4; ++l) {
    k_gemm_mfma<<<gemm_blocks, 256, 0, stream>>>(hhi, hlo,
        wphi + (size_t)(l - 1) * 16384, wplo + (size_t)(l - 1) * 16384, t, N);
    k_aggregate<<<nwb, 256, 0, stream>>>(t, rowptr, esrc, eww, dinv, bs + (size_t)l * 128,
                                         hhi, hlo, N, (l < 3) ? 1 : 0);
  }
  k_pool_partial<<<(N + 63) / 64, 256, 0, stream>>>(hhi, hlo, batch, pooled, N);
  k_out<<<G, 128, 0, stream>>>(pooled, gstart, gend, W_out, b_out, out, G);
}

// Round 5
// 473.340 us; speedup vs baseline: 1.8559x; 1.1511x over previous
//
#include <hip/hip_runtime.h>

typedef __attribute__((ext_vector_type(8))) short bf16x8;
typedef __attribute__((ext_vector_type(4))) float f32x4;

// bf16 round-to-nearest-even
__device__ inline unsigned short bf16_rtn(float f) {
  unsigned u = __float_as_uint(f);
  unsigned r = u + 0x7fffu + ((u >> 16) & 1u);
  return (unsigned short)(r >> 16);
}

// split fp32 into hi/lo bf16 (RTN split; hi+lo ≈ f to ~2^-17 rel)
__device__ inline void split_bf16(float f, unsigned short& hi, unsigned short& lo) {
  hi = bf16_rtn(f);
  float fh = __uint_as_float((unsigned)hi << 16);
  lo = bf16_rtn(f - fh);
}

__device__ inline float recon_bf16(unsigned short hi, unsigned short lo) {
  return __uint_as_float((unsigned)hi << 16) + __uint_as_float((unsigned)lo << 16);
}

__device__ inline float bf16_to_f(unsigned short v) {
  return __uint_as_float((unsigned)v << 16);
}

// ---------------- CSR construction ----------------

__global__ void k_hist(const int* __restrict__ dst, int* __restrict__ deg, int E) {
  int e = blockIdx.x * 256 + threadIdx.x;
  if (e < E) atomicAdd(&deg[dst[e]], 1);
}

__global__ void k_dinv(const int* __restrict__ deg, float* __restrict__ dinv, int N) {
  int i = blockIdx.x * 256 + threadIdx.x;
  if (i < N) dinv[i] = rsqrtf((float)deg[i] + 1.0f);
}

__global__ void k_scan1(const int* __restrict__ deg, int* __restrict__ rowptr,
                        int* __restrict__ bsum, int N) {
  __shared__ int s[256];
  int t = threadIdx.x;
  int i = blockIdx.x * 256 + t;
  int v = (i < N) ? deg[i] : 0;
  s[t] = v;
  __syncthreads();
  for (int off = 1; off < 256; off <<= 1) {
    int u = (t >= off) ? s[t - off] : 0;
    __syncthreads();
    s[t] += u;
    __syncthreads();
  }
  if (i < N) rowptr[i] = s[t] - v;
  if (t == 255) bsum[blockIdx.x] = s[255];
}

__global__ void k_scan2(const int* __restrict__ bsum, int* __restrict__ boff, int nb) {
  __shared__ int s[512];
  int t = threadIdx.x;
  int v = (t < nb) ? bsum[t] : 0;
  s[t] = v;
  __syncthreads();
  for (int off = 1; off < 512; off <<= 1) {
    int u = (t >= off) ? s[t - off] : 0;
    __syncthreads();
    s[t] += u;
    __syncthreads();
  }
  boff[t] = s[t] - v;
}

__global__ void k_scan3(int* __restrict__ rowptr, const int* __restrict__ boff,
                        int* __restrict__ cursor, int N, int E) {
  int i = blockIdx.x * 256 + threadIdx.x;
  if (i < N) {
    int r = rowptr[i] + boff[i >> 8];
    rowptr[i] = r;
    cursor[i] = r;
  }
  if (i == 0) rowptr[N] = E;
}

__global__ void k_scatter(const int* __restrict__ src, const int* __restrict__ dst,
                          const float* __restrict__ dinv, int* __restrict__ cursor,
                          int* __restrict__ esrc, float* __restrict__ ew, int E) {
  int e = blockIdx.x * 256 + threadIdx.x;
  if (e >= E) return;
  int s = src[e], d = dst[e];
  float w = dinv[s] * dinv[d];
  int pos = atomicAdd(&cursor[d], 1);
  esrc[pos] = s;
  ew[pos] = w;
}

// ---------------- tiny precomputes ----------------

// T[r][c] = embed[r] @ W0  (2 x 128)
__global__ void k_T(const float* __restrict__ embed, const float* __restrict__ W0,
                    float* __restrict__ T) {
  int t = threadIdx.x;
  int r = t >> 7, c = t & 127;
  float acc = 0.f;
  for (int k = 0; k < 128; ++k)
    acc += embed[r * 128 + k] * W0[k * 128 + c];
  T[r * 128 + c] = acc;
}

// Pre-swizzle W (layers 1..3) into MFMA B-fragment order, split hi/lo.
__global__ void k_prepW(const float* __restrict__ Ws,
                        unsigned short* __restrict__ wphi,
                        unsigned short* __restrict__ wplo) {
  int l = blockIdx.x;              // 0..2 -> layers 1..3
  const float* W = Ws + (size_t)(l + 1) * 128 * 128;
  unsigned short* dh = wphi + (size_t)l * 16384;
  unsigned short* dl = wplo + (size_t)l * 16384;
  for (int idx = threadIdx.x; idx < 16384; idx += 256) {
    int j = idx & 7;
    int lane = (idx >> 3) & 63;
    int c = (idx >> 9) & 3;
    int ct = idx >> 11;
    int k = c * 32 + ((lane >> 4) * 8) + j;
    int n = ct * 16 + (lane & 15);
    unsigned short hi, lo;
    split_bf16(W[k * 128 + n], hi, lo);
    dh[idx] = hi;
    dl[idx] = lo;
  }
}

__global__ void k_initb(int* gstart, int* gend, float* pooled, int G) {
  int g = blockIdx.x * 256 + threadIdx.x;
  if (g < G) { gstart[g] = 0; gend[g] = 0; }
  if (g < G * 128) pooled[g] = 0.f;
}

__global__ void k_bounds(const int* __restrict__ batch, int* __restrict__ gstart,
                         int* __restrict__ gend, int N) {
  int i = blockIdx.x * 256 + threadIdx.x;
  if (i >= N) return;
  int g = batch[i];
  if (i == 0 || batch[i - 1] != g) gstart[g] = i;
  if (i == N - 1 || batch[i + 1] != g) gend[g] = i + 1;
}

// ---------------- layer 0 (rank-2 shortcut) ----------------
__global__ void k_layer1(const int* __restrict__ x, const int* __restrict__ rowptr,
                         const int* __restrict__ esrc, const float* __restrict__ ew,
                         const float* __restrict__ dinv, const float* __restrict__ T,
                         const float* __restrict__ b0,
                         unsigned short* __restrict__ hhi,
                         unsigned short* __restrict__ hlo, int N) {
  int wid = (blockIdx.x * blockDim.x + threadIdx.x) >> 6;
  int lane = threadIdx.x & 63;
  if (wid >= N) return;
  int i = wid;
  int r0 = rowptr[i], r1 = rowptr[i + 1];
  float c0 = 0.f, c1 = 0.f;
  for (int e = r0 + lane; e < r1; e += 64) {
    float w = ew[e];
    int s = esrc[e];
    if (x[s]) c1 += w; else c0 += w;
  }
  for (int m = 32; m >= 1; m >>= 1) {
    c0 += __shfl_xor(c0, m, 64);
    c1 += __shfl_xor(c1, m, 64);
  }
  float di = dinv[i];
  float sn = di * di;
  if (x[i]) c1 += sn; else c0 += sn;
  for (int j = lane; j < 128; j += 64) {
    float v = c0 * T[j] + c1 * T[128 + j] + b0[j];
    v = fmaxf(v, 0.f);
    unsigned short hi, lo;
    split_bf16(v, hi, lo);
    hhi[(size_t)i * 128 + j] = hi;
    hlo[(size_t)i * 128 + j] = lo;
  }
}

// ---------------- MFMA split-bf16 GEMM: t = (hhi+hlo) @ W, t stored bf16 RTN ----------------
__global__ void k_gemm_mfma(const unsigned short* __restrict__ hhi,
                            const unsigned short* __restrict__ hlo,
                            const unsigned short* __restrict__ wphi,
                            const unsigned short* __restrict__ wplo,
                            unsigned short* __restrict__ thi, int N) {
  int wave = threadIdx.x >> 6;
  int lane = threadIdx.x & 63;
  int job = blockIdx.x * 4 + wave;
  int r0 = job * 32;
  if (r0 >= N) return;
  int q = lane >> 4;
  int m = lane & 15;

  f32x4 acc[2][8];
  #pragma unroll
  for (int tt = 0; tt < 2; ++tt)
    #pragma unroll
    for (int ct = 0; ct < 8; ++ct)
      acc[tt][ct] = (f32x4){0.f, 0.f, 0.f, 0.f};

  const bf16x8* bh_base = (const bf16x8*)wphi;
  const bf16x8* bl_base = (const bf16x8*)wplo;

  for (int c = 0; c < 4; ++c) {
    size_t ka = (size_t)(r0 + m) * 128 + c * 32 + q * 8;
    size_t kb = (size_t)(r0 + 16 + m) * 128 + c * 32 + q * 8;
    bf16x8 ah0 = *(const bf16x8*)(hhi + ka);
    bf16x8 al0 = *(const bf16x8*)(hlo + ka);
    bf16x8 ah1 = *(const bf16x8*)(hhi + kb);
    bf16x8 al1 = *(const bf16x8*)(hlo + kb);
    #pragma unroll
    for (int ct = 0; ct < 8; ++ct) {
      bf16x8 bh = bh_base[(ct * 4 + c) * 64 + lane];
      bf16x8 bl = bl_base[(ct * 4 + c) * 64 + lane];
      acc[0][ct] = __builtin_amdgcn_mfma_f32_16x16x32_bf16(ah0, bh, acc[0][ct], 0, 0, 0);
      acc[0][ct] = __builtin_amdgcn_mfma_f32_16x16x32_bf16(al0, bh, acc[0][ct], 0, 0, 0);
      acc[0][ct] = __builtin_amdgcn_mfma_f32_16x16x32_bf16(ah0, bl, acc[0][ct], 0, 0, 0);
      acc[1][ct] = __builtin_amdgcn_mfma_f32_16x16x32_bf16(ah1, bh, acc[1][ct], 0, 0, 0);
      acc[1][ct] = __builtin_amdgcn_mfma_f32_16x16x32_bf16(al1, bh, acc[1][ct], 0, 0, 0);
      acc[1][ct] = __builtin_amdgcn_mfma_f32_16x16x32_bf16(ah1, bl, acc[1][ct], 0, 0, 0);
    }
  }

  #pragma unroll
  for (int tt = 0; tt < 2; ++tt)
    #pragma unroll
    for (int ct = 0; ct < 8; ++ct)
      #pragma unroll
      for (int r = 0; r < 4; ++r) {
        int row = r0 + tt * 16 + q * 4 + r;
        thi[(size_t)row * 128 + ct * 16 + m] = bf16_rtn(acc[tt][ct][r]);
      }
}

// ---------------- aggregate: h = [relu](A_hat t + b), t is bf16; h written hi/lo ----------------
// One wave per node. Lane covers columns 2*lane, 2*lane+1 (ushort2 per row read).
// Edge (src,w) preloaded into lanes, shfl-broadcast -> independent gathers.
__global__ void k_aggregate(const unsigned short* __restrict__ thi,
                            const int* __restrict__ rowptr,
                            const int* __restrict__ esrc, const float* __restrict__ ew,
                            const float* __restrict__ dinv, const float* __restrict__ bvec,
                            unsigned short* __restrict__ hhi,
                            unsigned short* __restrict__ hlo, int N, int dorelu) {
  int wid = (blockIdx.x * blockDim.x + threadIdx.x) >> 6;
  int lane = threadIdx.x & 63;
  if (wid >= N) return;
  int i = wid;
  int r0 = rowptr[i], r1 = rowptr[i + 1];
  int deg = r1 - r0;

  int sl = 0; float wl = 0.f;
  if (lane < deg) {
    sl = esrc[r0 + lane];
    wl = ew[r0 + lane];
  }
  int dcap = deg < 64 ? deg : 64;

  float a0 = 0.f, a1 = 0.f;
  for (int e = 0; e < dcap; ++e) {
    int s = __shfl(sl, e, 64);
    float w = __shfl(wl, e, 64);
    unsigned p = *(const unsigned*)(thi + (size_t)s * 128 + 2 * lane);
    a0 += w * bf16_to_f((unsigned short)(p & 0xffffu));
    a1 += w * bf16_to_f((unsigned short)(p >> 16));
  }
  for (int e = r0 + 64; e < r1; ++e) {   // rare: deg > 64
    int s = esrc[e];
    float w = ew[e];
    unsigned p = *(const unsigned*)(thi + (size_t)s * 128 + 2 * lane);
    a0 += w * bf16_to_f((unsigned short)(p & 0xffffu));
    a1 += w * bf16_to_f((unsigned short)(p >> 16));
  }

  float di = dinv[i];
  float sn = di * di;
  unsigned ps = *(const unsigned*)(thi + (size_t)i * 128 + 2 * lane);
  a0 += sn * bf16_to_f((unsigned short)(ps & 0xffffu));
  a1 += sn * bf16_to_f((unsigned short)(ps >> 16));
  float2 bv = *(const float2*)(bvec + 2 * lane);
  a0 += bv.x;
  a1 += bv.y;
  if (dorelu) { a0 = fmaxf(a0, 0.f); a1 = fmaxf(a1, 0.f); }

  unsigned short h0, l0, h1, l1;
  split_bf16(a0, h0, l0);
  split_bf16(a1, h1, l1);
  *(unsigned*)(hhi + (size_t)i * 128 + 2 * lane) = (unsigned)h0 | ((unsigned)h1 << 16);
  *(unsigned*)(hlo + (size_t)i * 128 + 2 * lane) = (unsigned)l0 | ((unsigned)l1 << 16);
}

// ---------------- mean-pool: parallel partial sums ----------------
__global__ void k_pool_partial(const unsigned short* __restrict__ hhi,
                               const unsigned short* __restrict__ hlo,
                               const int* __restrict__ batch,
                               float* __restrict__ pooled, int N) {
  int c = threadIdx.x & 127;
  int half = threadIdx.x >> 7;
  int rbeg = blockIdx.x * 64 + half * 32;
  int rend = rbeg + 32;
  if (rend > N) rend = N;
  if (rbeg >= N) return;
  float acc = 0.f;
  int curg = batch[rbeg];
  for (int i = rbeg; i < rend; ++i) {
    int g = batch[i];
    if (g != curg) {
      atomicAdd(&pooled[curg * 128 + c], acc);
      acc = 0.f;
      curg = g;
    }
    acc += recon_bf16(hhi[(size_t)i * 128 + c], hlo[(size_t)i * 128 + c]);
  }
  atomicAdd(&pooled[curg * 128 + c], acc);
}

// ---------------- output head ----------------
__global__ void k_out(const float* __restrict__ pooled, const int* __restrict__ gstart,
                      const int* __restrict__ gend, const float* __restrict__ W_out,
                      const float* __restrict__ b_out, float* __restrict__ out, int G) {
  __shared__ float sp[128];
  int g = blockIdx.x;
  int j = threadIdx.x;
  float cnt = (float)(gend[g] - gstart[g]);
  sp[j] = pooled[g * 128 + j] / fmaxf(cnt, 1.f);
  __syncthreads();
  if (j < 2) {
    float o = b_out[j];
    for (int k = 0; k < 128; ++k)
      o += sp[k] * W_out[k * 2 + j];
    out[g * 2 + j] = o;
  }
}

extern "C" void kernel_launch(void* const* d_in, const int* in_sizes, int n_in,
                              void* d_out, int out_size, void* d_ws, size_t ws_size,
                              hipStream_t stream) {
  const int*   x     = (const int*)d_in[0];
  const int*   ei    = (const int*)d_in[1];
  const int*   batch = (const int*)d_in[2];
  const float* embed = (const float*)d_in[3];
  const float* Ws    = (const float*)d_in[4];
  const float* bs    = (const float*)d_in[5];
  const float* W_out = (const float*)d_in[6];
  const float* b_out = (const float*)d_in[7];
  float* out = (float*)d_out;

  int N = in_sizes[2];
  int E = in_sizes[1] / 2;
  int G = out_size / 2;

  const int* src = ei;
  const int* dst = ei + E;

  char* w = (char*)d_ws;
  auto alloc = [&](size_t bytes) {
    char* p = w;
    w += (bytes + 255) & ~(size_t)255;
    return p;
  };
  int*   deg    = (int*)  alloc((size_t)N * 4);
  float* dinv   = (float*)alloc((size_t)N * 4);
  int*   rowptr = (int*)  alloc((size_t)(N + 1) * 4);
  int*   cursor = (int*)  alloc((size_t)N * 4);
  int*   bsum   = (int*)  alloc(512 * 4);
  int*   boff   = (int*)  alloc(512 * 4);
  int*   gstart = (int*)  alloc((size_t)G * 4);
  int*   gend   = (int*)  alloc((size_t)G * 4);
  float* T      = (float*)alloc(256 * 4);
  float* pooled = (float*)alloc((size_t)G * 128 * 4);
  unsigned short* wphi = (unsigned short*)alloc((size_t)3 * 16384 * 2);
  unsigned short* wplo = (unsigned short*)alloc((size_t)3 * 16384 * 2);
  int*   esrc   = (int*)  alloc((size_t)E * 4);
  float* eww    = (float*)alloc((size_t)E * 4);
  unsigned short* hhi = (unsigned short*)alloc((size_t)N * 128 * 2);
  unsigned short* hlo = (unsigned short*)alloc((size_t)N * 128 * 2);
  unsigned short* thi = (unsigned short*)alloc((size_t)N * 128 * 2);

  int nbN = (N + 255) / 256;
  int nbE = (E + 255) / 256;
  int nwb = (N + 3) / 4;

  hipMemsetAsync(deg, 0, (size_t)N * 4, stream);
  k_hist<<<nbE, 256, 0, stream>>>(dst, deg, E);
  k_dinv<<<nbN, 256, 0, stream>>>(deg, dinv, N);
  k_scan1<<<nbN, 256, 0, stream>>>(deg, rowptr, bsum, N);
  k_scan2<<<1, 512, 0, stream>>>(bsum, boff, nbN);
  k_scan3<<<nbN, 256, 0, stream>>>(rowptr, boff, cursor, N, E);
  k_scatter<<<nbE, 256, 0, stream>>>(src, dst, dinv, cursor, esrc, eww, E);
  k_T<<<1, 256, 0, stream>>>(embed, Ws, T);
  k_prepW<<<3, 256, 0, stream>>>(Ws, wphi, wplo);
  k_initb<<<(G * 128 + 255) / 256, 256, 0, stream>>>(gstart, gend, pooled, G);
  k_bounds<<<nbN, 256, 0, stream>>>(batch, gstart, gend, N);

  k_layer1<<<nwb, 256, 0, stream>>>(x, rowptr, esrc, eww, dinv, T, bs, hhi, hlo, N);

  int gemm_blocks = (N / 32 + 3) / 4 + 1;
  for (int l = 1; l < 4; ++l) {
    k_gemm_mfma<<<gemm_blocks, 256, 0, stream>>>(hhi, hlo,
        wphi + (size_t)(l - 1) * 16384, wplo + (size_t)(l - 1) * 16384, thi, N);
    k_aggregate<<<nwb, 256, 0, stream>>>(thi, rowptr, esrc, eww, dinv, bs + (size_t)l * 128,
                                         hhi, hlo, N, (l < 3) ? 1 : 0);
  }
  k_pool_partial<<<(N + 63) / 64, 256, 0, stream>>>(hhi, hlo, batch, pooled, N);
  k_out<<<G, 128, 0, stream>>>(pooled, gstart, gend, W_out, b_out, out, G);
}

// Round 6
// 405.787 us; speedup vs baseline: 2.1648x; 1.1665x over previous
//
#include <hip/hip_runtime.h>

typedef __attribute__((ext_vector_type(8))) short bf16x8;
typedef __attribute__((ext_vector_type(4))) float f32x4;

// bf16 round-to-nearest-even
__device__ inline unsigned short bf16_rtn(float f) {
  unsigned u = __float_as_uint(f);
  unsigned r = u + 0x7fffu + ((u >> 16) & 1u);
  return (unsigned short)(r >> 16);
}

// split fp32 into hi/lo bf16 (for W only)
__device__ inline void split_bf16(float f, unsigned short& hi, unsigned short& lo) {
  hi = bf16_rtn(f);
  float fh = __uint_as_float((unsigned)hi << 16);
  lo = bf16_rtn(f - fh);
}

__device__ inline float bf16_to_f(unsigned short v) {
  return __uint_as_float((unsigned)v << 16);
}

// ---------------- CSR construction ----------------

__global__ void k_hist(const int* __restrict__ dst, int* __restrict__ deg, int E) {
  int e = blockIdx.x * 256 + threadIdx.x;
  if (e < E) atomicAdd(&deg[dst[e]], 1);
}

__global__ void k_dinv(const int* __restrict__ deg, float* __restrict__ dinv, int N) {
  int i = blockIdx.x * 256 + threadIdx.x;
  if (i < N) dinv[i] = rsqrtf((float)deg[i] + 1.0f);
}

__global__ void k_scan1(const int* __restrict__ deg, int* __restrict__ rowptr,
                        int* __restrict__ bsum, int N) {
  __shared__ int s[256];
  int t = threadIdx.x;
  int i = blockIdx.x * 256 + t;
  int v = (i < N) ? deg[i] : 0;
  s[t] = v;
  __syncthreads();
  for (int off = 1; off < 256; off <<= 1) {
    int u = (t >= off) ? s[t - off] : 0;
    __syncthreads();
    s[t] += u;
    __syncthreads();
  }
  if (i < N) rowptr[i] = s[t] - v;
  if (t == 255) bsum[blockIdx.x] = s[255];
}

__global__ void k_scan2(const int* __restrict__ bsum, int* __restrict__ boff, int nb) {
  __shared__ int s[512];
  int t = threadIdx.x;
  int v = (t < nb) ? bsum[t] : 0;
  s[t] = v;
  __syncthreads();
  for (int off = 1; off < 512; off <<= 1) {
    int u = (t >= off) ? s[t - off] : 0;
    __syncthreads();
    s[t] += u;
    __syncthreads();
  }
  boff[t] = s[t] - v;
}

__global__ void k_scan3(int* __restrict__ rowptr, const int* __restrict__ boff,
                        int* __restrict__ cursor, int N, int E) {
  int i = blockIdx.x * 256 + threadIdx.x;
  if (i < N) {
    int r = rowptr[i] + boff[i >> 8];
    rowptr[i] = r;
    cursor[i] = r;
  }
  if (i == 0) rowptr[N] = E;
}

__global__ void k_scatter(const int* __restrict__ src, const int* __restrict__ dst,
                          const float* __restrict__ dinv, int* __restrict__ cursor,
                          int* __restrict__ esrc, float* __restrict__ ew, int E) {
  int e = blockIdx.x * 256 + threadIdx.x;
  if (e >= E) return;
  int s = src[e], d = dst[e];
  float w = dinv[s] * dinv[d];
  int pos = atomicAdd(&cursor[d], 1);
  esrc[pos] = s;
  ew[pos] = w;
}

// ---------------- tiny precomputes ----------------

// T[r][c] = embed[r] @ W0  (2 x 128)
__global__ void k_T(const float* __restrict__ embed, const float* __restrict__ W0,
                    float* __restrict__ T) {
  int t = threadIdx.x;
  int r = t >> 7, c = t & 127;
  float acc = 0.f;
  for (int k = 0; k < 128; ++k)
    acc += embed[r * 128 + k] * W0[k * 128 + c];
  T[r * 128 + c] = acc;
}

// Pre-swizzle W (layers 1..3) into MFMA B-fragment order, split hi/lo.
// idx = ((ct*4 + c)*64 + lane)*8 + j  ->  W[k][n], k = c*32+(lane>>4)*8+j, n = ct*16+(lane&15)
__global__ void k_prepW(const float* __restrict__ Ws,
                        unsigned short* __restrict__ wphi,
                        unsigned short* __restrict__ wplo) {
  int l = blockIdx.x;              // 0..2 -> layers 1..3
  const float* W = Ws + (size_t)(l + 1) * 128 * 128;
  unsigned short* dh = wphi + (size_t)l * 16384;
  unsigned short* dl = wplo + (size_t)l * 16384;
  for (int idx = threadIdx.x; idx < 16384; idx += 256) {
    int j = idx & 7;
    int lane = (idx >> 3) & 63;
    int c = (idx >> 9) & 3;
    int ct = idx >> 11;
    int k = c * 32 + ((lane >> 4) * 8) + j;
    int n = ct * 16 + (lane & 15);
    unsigned short hi, lo;
    split_bf16(W[k * 128 + n], hi, lo);
    dh[idx] = hi;
    dl[idx] = lo;
  }
}

__global__ void k_initb(int* gstart, int* gend, float* pooled, int G) {
  int g = blockIdx.x * 256 + threadIdx.x;
  if (g < G) { gstart[g] = 0; gend[g] = 0; }
  if (g < G * 128) pooled[g] = 0.f;
}

__global__ void k_bounds(const int* __restrict__ batch, int* __restrict__ gstart,
                         int* __restrict__ gend, int N) {
  int i = blockIdx.x * 256 + threadIdx.x;
  if (i >= N) return;
  int g = batch[i];
  if (i == 0 || batch[i - 1] != g) gstart[g] = i;
  if (i == N - 1 || batch[i + 1] != g) gend[g] = i + 1;
}

// ---------------- shared MFMA phase: t_out tile = hT(LDS) @ W' ----------------
// hT: 32 rows x 136 shorts (pad 8 -> 16B-aligned rows, 2-way LDS banks).
// Wave handles ct = {2*wave, 2*wave+1}; 2 MFMAs per step (A bf16 exact, B hi+lo).
__device__ inline void gemm_tile(const unsigned short* hT,
                                 const unsigned short* __restrict__ wphi,
                                 const unsigned short* __restrict__ wplo,
                                 unsigned short* __restrict__ tout, int i0, int N) {
  int wave = threadIdx.x >> 6;
  int lane = threadIdx.x & 63;
  int q = lane >> 4;
  int m = lane & 15;
  const bf16x8* bh_base = (const bf16x8*)wphi;
  const bf16x8* bl_base = (const bf16x8*)wplo;

  f32x4 acc[2][2];
  #pragma unroll
  for (int tt = 0; tt < 2; ++tt)
    #pragma unroll
    for (int cc = 0; cc < 2; ++cc)
      acc[tt][cc] = (f32x4){0.f, 0.f, 0.f, 0.f};

  #pragma unroll
  for (int c = 0; c < 4; ++c) {
    bf16x8 a0 = *(const bf16x8*)(hT + (m) * 136 + c * 32 + q * 8);
    bf16x8 a1 = *(const bf16x8*)(hT + (16 + m) * 136 + c * 32 + q * 8);
    #pragma unroll
    for (int cc = 0; cc < 2; ++cc) {
      int ct = wave * 2 + cc;
      bf16x8 bh = bh_base[(ct * 4 + c) * 64 + lane];
      bf16x8 bl = bl_base[(ct * 4 + c) * 64 + lane];
      acc[0][cc] = __builtin_amdgcn_mfma_f32_16x16x32_bf16(a0, bh, acc[0][cc], 0, 0, 0);
      acc[0][cc] = __builtin_amdgcn_mfma_f32_16x16x32_bf16(a0, bl, acc[0][cc], 0, 0, 0);
      acc[1][cc] = __builtin_amdgcn_mfma_f32_16x16x32_bf16(a1, bh, acc[1][cc], 0, 0, 0);
      acc[1][cc] = __builtin_amdgcn_mfma_f32_16x16x32_bf16(a1, bl, acc[1][cc], 0, 0, 0);
    }
  }

  #pragma unroll
  for (int tt = 0; tt < 2; ++tt)
    #pragma unroll
    for (int cc = 0; cc < 2; ++cc)
      #pragma unroll
      for (int r = 0; r < 4; ++r) {
        int row = i0 + tt * 16 + q * 4 + r;
        if (row < N)
          tout[(size_t)row * 128 + (wave * 2 + cc) * 16 + m] = bf16_rtn(acc[tt][cc][r]);
      }
}

// ---------------- fused layer0 (rank-2) + gemm1: t1 = h1 @ W1 ----------------
__global__ void k_l1_gemm(const int* __restrict__ x, const int* __restrict__ rowptr,
                          const int* __restrict__ esrc, const float* __restrict__ ew,
                          const float* __restrict__ dinv, const float* __restrict__ T,
                          const float* __restrict__ b0,
                          const unsigned short* __restrict__ wphi,
                          const unsigned short* __restrict__ wplo,
                          unsigned short* __restrict__ tout, int N) {
  __shared__ unsigned short hT[32 * 136];
  int wave = threadIdx.x >> 6;
  int lane = threadIdx.x & 63;
  int i0 = blockIdx.x * 32;

  for (int j = wave * 8; j < wave * 8 + 8; ++j) {
    int i = i0 + j;
    if (i >= N) break;
    int r0 = rowptr[i], r1 = rowptr[i + 1];
    float c0 = 0.f, c1 = 0.f;
    for (int e = r0 + lane; e < r1; e += 64) {
      float w = ew[e];
      int s = esrc[e];
      if (x[s]) c1 += w; else c0 += w;
    }
    for (int mm = 32; mm >= 1; mm >>= 1) {
      c0 += __shfl_xor(c0, mm, 64);
      c1 += __shfl_xor(c1, mm, 64);
    }
    float di = dinv[i];
    float sn = di * di;
    if (x[i]) c1 += sn; else c0 += sn;
    float v0 = fmaxf(c0 * T[2 * lane]     + c1 * T[128 + 2 * lane]     + b0[2 * lane],     0.f);
    float v1 = fmaxf(c0 * T[2 * lane + 1] + c1 * T[128 + 2 * lane + 1] + b0[2 * lane + 1], 0.f);
    *(unsigned*)&hT[j * 136 + 2 * lane] = (unsigned)bf16_rtn(v0) | ((unsigned)bf16_rtn(v1) << 16);
  }
  __syncthreads();
  gemm_tile(hT, wphi, wplo, tout, i0, N);
}

// ---------------- fused aggregate + gemm: t_next = relu(A t_in + b) @ W' ----------------
__global__ void k_agg_gemm(const unsigned short* __restrict__ tin,
                           const int* __restrict__ rowptr,
                           const int* __restrict__ esrc, const float* __restrict__ ew,
                           const float* __restrict__ dinv, const float* __restrict__ bvec,
                           const unsigned short* __restrict__ wphi,
                           const unsigned short* __restrict__ wplo,
                           unsigned short* __restrict__ tout, int N) {
  __shared__ unsigned short hT[32 * 136];
  int wave = threadIdx.x >> 6;
  int lane = threadIdx.x & 63;
  int i0 = blockIdx.x * 32;
  float2 bv = *(const float2*)(bvec + 2 * lane);

  for (int j = wave * 8; j < wave * 8 + 8; ++j) {
    int i = i0 + j;
    if (i >= N) break;
    int r0 = rowptr[i], r1 = rowptr[i + 1];
    int deg = r1 - r0;
    int sl = 0; float wl = 0.f;
    if (lane < deg) { sl = esrc[r0 + lane]; wl = ew[r0 + lane]; }
    int dcap = deg < 64 ? deg : 64;
    float a0 = 0.f, a1 = 0.f;
    for (int e = 0; e < dcap; ++e) {
      int s = __shfl(sl, e, 64);
      float w = __shfl(wl, e, 64);
      unsigned p = *(const unsigned*)(tin + (size_t)s * 128 + 2 * lane);
      a0 += w * bf16_to_f((unsigned short)(p & 0xffffu));
      a1 += w * bf16_to_f((unsigned short)(p >> 16));
    }
    for (int e = r0 + 64; e < r1; ++e) {   // rare: deg > 64
      int s = esrc[e];
      float w = ew[e];
      unsigned p = *(const unsigned*)(tin + (size_t)s * 128 + 2 * lane);
      a0 += w * bf16_to_f((unsigned short)(p & 0xffffu));
      a1 += w * bf16_to_f((unsigned short)(p >> 16));
    }
    float di = dinv[i];
    float sn = di * di;
    unsigned ps = *(const unsigned*)(tin + (size_t)i * 128 + 2 * lane);
    a0 += sn * bf16_to_f((unsigned short)(ps & 0xffffu));
    a1 += sn * bf16_to_f((unsigned short)(ps >> 16));
    a0 = fmaxf(a0 + bv.x, 0.f);
    a1 = fmaxf(a1 + bv.y, 0.f);
    *(unsigned*)&hT[j * 136 + 2 * lane] = (unsigned)bf16_rtn(a0) | ((unsigned)bf16_rtn(a1) << 16);
  }
  __syncthreads();
  gemm_tile(hT, wphi, wplo, tout, i0, N);
}

// ---------------- fused final aggregate + segment mean-pool ----------------
__global__ void k_agg_pool(const unsigned short* __restrict__ tin,
                           const int* __restrict__ rowptr,
                           const int* __restrict__ esrc, const float* __restrict__ ew,
                           const float* __restrict__ dinv, const float* __restrict__ bvec,
                           const int* __restrict__ batch,
                           float* __restrict__ pooled, int N) {
  int wave = threadIdx.x >> 6;
  int lane = threadIdx.x & 63;
  int i0 = blockIdx.x * 32;
  int jbeg = wave * 8;
  if (i0 + jbeg >= N) return;
  float2 bv = *(const float2*)(bvec + 2 * lane);

  float acc0 = 0.f, acc1 = 0.f;
  int curg = batch[i0 + jbeg];
  for (int j = jbeg; j < jbeg + 8; ++j) {
    int i = i0 + j;
    if (i >= N) break;
    int r0 = rowptr[i], r1 = rowptr[i + 1];
    int deg = r1 - r0;
    int sl = 0; float wl = 0.f;
    if (lane < deg) { sl = esrc[r0 + lane]; wl = ew[r0 + lane]; }
    int dcap = deg < 64 ? deg : 64;
    float a0 = 0.f, a1 = 0.f;
    for (int e = 0; e < dcap; ++e) {
      int s = __shfl(sl, e, 64);
      float w = __shfl(wl, e, 64);
      unsigned p = *(const unsigned*)(tin + (size_t)s * 128 + 2 * lane);
      a0 += w * bf16_to_f((unsigned short)(p & 0xffffu));
      a1 += w * bf16_to_f((unsigned short)(p >> 16));
    }
    for (int e = r0 + 64; e < r1; ++e) {
      int s = esrc[e];
      float w = ew[e];
      unsigned p = *(const unsigned*)(tin + (size_t)s * 128 + 2 * lane);
      a0 += w * bf16_to_f((unsigned short)(p & 0xffffu));
      a1 += w * bf16_to_f((unsigned short)(p >> 16));
    }
    float di = dinv[i];
    float sn = di * di;
    unsigned ps = *(const unsigned*)(tin + (size_t)i * 128 + 2 * lane);
    a0 += sn * bf16_to_f((unsigned short)(ps & 0xffffu)) + bv.x;
    a1 += sn * bf16_to_f((unsigned short)(ps >> 16)) + bv.y;
    int g = batch[i];
    if (g != curg) {
      atomicAdd(&pooled[curg * 128 + 2 * lane], acc0);
      atomicAdd(&pooled[curg * 128 + 2 * lane + 1], acc1);
      acc0 = 0.f; acc1 = 0.f;
      curg = g;
    }
    acc0 += a0;
    acc1 += a1;
  }
  atomicAdd(&pooled[curg * 128 + 2 * lane], acc0);
  atomicAdd(&pooled[curg * 128 + 2 * lane + 1], acc1);
}

// ---------------- output head ----------------
__global__ void k_out(const float* __restrict__ pooled, const int* __restrict__ gstart,
                      const int* __restrict__ gend, const float* __restrict__ W_out,
                      const float* __restrict__ b_out, float* __restrict__ out, int G) {
  __shared__ float sp[128];
  int g = blockIdx.x;
  int j = threadIdx.x;
  float cnt = (float)(gend[g] - gstart[g]);
  sp[j] = pooled[g * 128 + j] / fmaxf(cnt, 1.f);
  __syncthreads();
  if (j < 2) {
    float o = b_out[j];
    for (int k = 0; k < 128; ++k)
      o += sp[k] * W_out[k * 2 + j];
    out[g * 2 + j] = o;
  }
}

extern "C" void kernel_launch(void* const* d_in, const int* in_sizes, int n_in,
                              void* d_out, int out_size, void* d_ws, size_t ws_size,
                              hipStream_t stream) {
  const int*   x     = (const int*)d_in[0];
  const int*   ei    = (const int*)d_in[1];
  const int*   batch = (const int*)d_in[2];
  const float* embed = (const float*)d_in[3];
  const float* Ws    = (const float*)d_in[4];
  const float* bs    = (const float*)d_in[5];
  const float* W_out = (const float*)d_in[6];
  const float* b_out = (const float*)d_in[7];
  float* out = (float*)d_out;

  int N = in_sizes[2];
  int E = in_sizes[1] / 2;
  int G = out_size / 2;

  const int* src = ei;
  const int* dst = ei + E;

  char* w = (char*)d_ws;
  auto alloc = [&](size_t bytes) {
    char* p = w;
    w += (bytes + 255) & ~(size_t)255;
    return p;
  };
  int*   deg    = (int*)  alloc((size_t)N * 4);
  float* dinv   = (float*)alloc((size_t)N * 4);
  int*   rowptr = (int*)  alloc((size_t)(N + 1) * 4);
  int*   cursor = (int*)  alloc((size_t)N * 4);
  int*   bsum   = (int*)  alloc(512 * 4);
  int*   boff   = (int*)  alloc(512 * 4);
  int*   gstart = (int*)  alloc((size_t)G * 4);
  int*   gend   = (int*)  alloc((size_t)G * 4);
  float* T      = (float*)alloc(256 * 4);
  float* pooled = (float*)alloc((size_t)G * 128 * 4);
  unsigned short* wphi = (unsigned short*)alloc((size_t)3 * 16384 * 2);
  unsigned short* wplo = (unsigned short*)alloc((size_t)3 * 16384 * 2);
  int*   esrc   = (int*)  alloc((size_t)E * 4);
  float* eww    = (float*)alloc((size_t)E * 4);
  unsigned short* t_a = (unsigned short*)alloc((size_t)N * 128 * 2);
  unsigned short* t_b = (unsigned short*)alloc((size_t)N * 128 * 2);

  int nbN = (N + 255) / 256;
  int nbE = (E + 255) / 256;
  int ntile = (N + 31) / 32;

  hipMemsetAsync(deg, 0, (size_t)N * 4, stream);
  k_hist<<<nbE, 256, 0, stream>>>(dst, deg, E);
  k_dinv<<<nbN, 256, 0, stream>>>(deg, dinv, N);
  k_scan1<<<nbN, 256, 0, stream>>>(deg, rowptr, bsum, N);
  k_scan2<<<1, 512, 0, stream>>>(bsum, boff, nbN);
  k_scan3<<<nbN, 256, 0, stream>>>(rowptr, boff, cursor, N, E);
  k_scatter<<<nbE, 256, 0, stream>>>(src, dst, dinv, cursor, esrc, eww, E);
  k_T<<<1, 256, 0, stream>>>(embed, Ws, T);
  k_prepW<<<3, 256, 0, stream>>>(Ws, wphi, wplo);
  k_initb<<<(G * 128 + 255) / 256, 256, 0, stream>>>(gstart, gend, pooled, G);
  k_bounds<<<nbN, 256, 0, stream>>>(batch, gstart, gend, N);

  // layer0 (rank-2) + gemm1 -> t_a
  k_l1_gemm<<<ntile, 256, 0, stream>>>(x, rowptr, esrc, eww, dinv, T, bs,
                                       wphi, wplo, t_a, N);
  // agg(b1)+gemm(W2) -> t_b ; agg(b2)+gemm(W3) -> t_a
  k_agg_gemm<<<ntile, 256, 0, stream>>>(t_a, rowptr, esrc, eww, dinv, bs + 128,
                                        wphi + 16384, wplo + 16384, t_b, N);
  k_agg_gemm<<<ntile, 256, 0, stream>>>(t_b, rowptr, esrc, eww, dinv, bs + 256,
                                        wphi + 32768, wplo + 32768, t_a, N);
  // final agg(b3) + mean-pool
  k_agg_pool<<<ntile, 256, 0, stream>>>(t_a, rowptr, esrc, eww, dinv, bs + 384,
                                        batch, pooled, N);
  k_out<<<G, 128, 0, stream>>>(pooled, gstart, gend, W_out, b_out, out, G);
}